// Round 7
// baseline (636.939 us; speedup 1.0000x reference)
//
#include <hip/hip_runtime.h>
#include <hip/hip_bf16.h>
#include <stdint.h>

#define N_CLAIM    100000
#define N_ENTITY   200000
#define N_EVIDENCE 150000
#define NEDGE      2000000
#define F          64
#define NT         550000      // concat dst: t0 claim [0,100K) t1 claim [100K,200K) t2 ent [200K,400K) t3 evid [400K,550K)
#define BATCH      50000

#define BSH   11               // 2048 nodes/bucket
#define NBKT  269              // ceil(550000/2048)
#define CAP   28672            // max bucket lambda ~27.3K (evidence) + 8 sigma
#define B3_BLOCKS 1024
#define B3_CHUNK  8192         // 1024*8192 >= 8M edges
#define B3_K      (B3_CHUNK/256)

static __device__ __forceinline__ float b2f(unsigned short u){
  return __uint_as_float(((unsigned int)u) << 16);
}
static __device__ __forceinline__ unsigned short f2b(float f){
  unsigned int x = __float_as_uint(f);
  x += 0x7fffu + ((x >> 16) & 1u);   // RNE
  return (unsigned short)(x >> 16);
}

// ---------------- fused fp32 -> bf16 cast (xb_c|xb_e|xb_v contiguous out) ----------------
__global__ void k_cast3(const float* __restrict__ a, const float* __restrict__ b,
                        const float* __restrict__ c, unsigned short* __restrict__ o){
  int i = blockIdx.x * blockDim.x + threadIdx.x;     // float4 index
  const int nc = N_CLAIM * F / 4, ne2 = nc + N_ENTITY * F / 4,
            nv2 = ne2 + N_EVIDENCE * F / 4;
  if (i >= nv2) return;
  const float* src; int off;
  if (i < nc){ src = a; off = i; }
  else if (i < ne2){ src = b; off = i - nc; }
  else { src = c; off = i - ne2; }
  float4 v = ((const float4*)src)[off];
  ushort4 u;
  u.x = f2b(v.x); u.y = f2b(v.y); u.z = f2b(v.z); u.w = f2b(v.w);
  ((ushort4*)o)[i] = u;
}

// ---------------- used-claim mask + cursor init ----------------
__global__ void k_mark(const int* __restrict__ cbi, int* __restrict__ flag,
                       int* __restrict__ cursor){
  int i = blockIdx.x * blockDim.x + threadIdx.x;
  if (i < BATCH) flag[cbi[i]] = 1;
  if (i < NBKT) cursor[i] = i * CAP;
}
__global__ void k_rank(const int* __restrict__ flag, int* __restrict__ rank,
                       int* __restrict__ list, int* __restrict__ nu){
  int i = blockIdx.x * blockDim.x + threadIdx.x;
  if (i < N_CLAIM && flag[i]){
    int r = atomicAdd(nu, 1);
    rank[i] = r;
    list[r] = i;
  }
}

// ---------------- CSR build: partitioned counting sort, ticket-in-register ----------------
// pass1: dst load + flag filter; hist atomic RETURNS per-edge rank (kept in VGPRs);
//        gdst cached in LDS. reserve: one global atomic per (block,bucket).
// pass2: NO LDS atomic: off = hpos[gdst>>BSH] + rank[k]; src load independent.
__global__ __launch_bounds__(256) void k_bscatter(const int* __restrict__ ei,
                                                  const int* __restrict__ flag,
                                                  int* __restrict__ cursor,
                                                  unsigned int* __restrict__ pairs){
  __shared__ int hcnt[NBKT];
  __shared__ int hpos[NBKT];
  __shared__ unsigned int ldst[B3_CHUNK];   // 32 KB: gdst, or ~0u = skip
  const int toff[4] = {0, N_CLAIM, 2*N_CLAIM, 2*N_CLAIM + N_ENTITY};
  int tid = threadIdx.x;
  int g0 = blockIdx.x * B3_CHUNK;
  int rank[B3_K];
  for (int b = tid; b < NBKT; b += 256) hcnt[b] = 0;
  __syncthreads();
  #pragma unroll
  for (int k = 0; k < B3_K; ++k){
    int li = k * 256 + tid;
    int g = g0 + li;
    unsigned int v = 0xFFFFFFFFu;
    rank[k] = 0;
    if (g < 4 * NEDGE){
      int t = g / NEDGE;
      int e = g - t * NEDGE;
      int dst = ei[t * 2 * NEDGE + NEDGE + e];
      bool keep = (t >= 2) || (flag[dst] != 0);
      if (keep){
        v = (unsigned int)(dst + toff[t]);
        rank[k] = atomicAdd(&hcnt[v >> BSH], 1);
      }
    }
    ldst[li] = v;
  }
  __syncthreads();
  for (int b = tid; b < NBKT; b += 256){
    int c = hcnt[b];
    hpos[b] = c ? atomicAdd(&cursor[b], c) : 0;
  }
  __syncthreads();
  #pragma unroll
  for (int k = 0; k < B3_K; ++k){
    int li = k * 256 + tid;
    int g = g0 + li;
    unsigned int v = ldst[li];
    if (v != 0xFFFFFFFFu){
      int t = g / NEDGE;
      int e = g - t * NEDGE;
      int src = ei[t * 2 * NEDGE + e];
      int off = hpos[v >> BSH] + rank[k];
      pairs[off] = ((v & ((1u << BSH) - 1)) << 18) | (unsigned int)src;
    }
  }
}

__global__ void k_bscan(const int* __restrict__ cursor, int* __restrict__ colBase,
                        int* __restrict__ R){
  __shared__ int s[1024];
  int tid = threadIdx.x;
  int c = (tid < NBKT) ? (cursor[tid] - tid * CAP) : 0;
  s[tid] = c;
  __syncthreads();
  for (int off = 1; off < 1024; off <<= 1){
    int t = (tid >= off) ? s[tid - off] : 0;
    __syncthreads();
    s[tid] += t;
    __syncthreads();
  }
  if (tid < NBKT) colBase[tid] = s[tid] - c;
  if (tid == 1023) R[NT] = s[1023];
}

// 4 sub-blocks per bucket: full-bucket hist + scan, place own 512-node quarter
__global__ __launch_bounds__(256) void k_csr(const unsigned int* __restrict__ pairs,
                                             const int* __restrict__ cursor,
                                             const int* __restrict__ colBase,
                                             int* __restrict__ R, int* __restrict__ col){
  __shared__ int h[2048];
  __shared__ int aux[256];
  int bid = blockIdx.x;
  int b = bid >> 2, sub = bid & 3;
  int tid = threadIdx.x;
  int cnt  = cursor[b] - b * CAP;
  int base = colBase[b];
  long long pbase = (long long)b * CAP;
  for (int j = tid; j < 2048; j += 256) h[j] = 0;
  __syncthreads();
  for (int i = tid; i < cnt; i += 256)
    atomicAdd(&h[pairs[pbase + i] >> 18], 1);
  __syncthreads();
  int j8 = tid * 8;
  int a[8]; int tsum = 0;
  #pragma unroll
  for (int k = 0; k < 8; k++){ a[k] = h[j8 + k]; tsum += a[k]; }
  aux[tid] = tsum;
  __syncthreads();
  for (int off = 1; off < 256; off <<= 1){
    int t = (tid >= off) ? aux[tid - off] : 0;
    __syncthreads();
    aux[tid] += t;
    __syncthreads();
  }
  int ex = aux[tid] - tsum;
  #pragma unroll
  for (int k = 0; k < 8; k++){ int t = a[k]; h[j8 + k] = ex; ex += t; }
  __syncthreads();
  int nodeBase = (b << BSH) + (sub << 9);
  for (int q = tid; q < 512; q += 256){
    int n = nodeBase + q;
    if (n < NT) R[n] = base + h[(sub << 9) + q];
  }
  __syncthreads();
  for (int i = tid; i < cnt; i += 256){
    unsigned int p = pairs[pbase + i];
    int ld = (int)(p >> 18);
    if ((ld >> 9) == sub){
      int r = atomicAdd(&h[ld], 1);
      col[base + r] = (int)(p & 0x3FFFFu);
    }
  }
}

// ---- mean aggregation (all dst types, one launch): 4 rows/wave, 16 lanes x 8B ----
// job j: [0,2nu) claims via list (sub 0/1 at nu); then entity [0,ne); then evidence [0,nev).
__global__ __launch_bounds__(256) void k_agg4(const unsigned short* __restrict__ X0,
                                              const unsigned short* __restrict__ X1,
                                              const unsigned short* __restrict__ X2,
                                              const unsigned short* __restrict__ X3,
                                              const int* __restrict__ R,
                                              const int* __restrict__ col,
                                              unsigned short* __restrict__ M0,
                                              unsigned short* __restrict__ M1,
                                              unsigned short* __restrict__ M2,
                                              unsigned short* __restrict__ M3,
                                              const int* __restrict__ list,
                                              const int* __restrict__ nu_ptr,
                                              int ne, int nev){
  int tid  = threadIdx.x;
  int lane = tid & 63;
  int g    = lane >> 4;
  int fl   = lane & 15;
  int wv   = (int)blockIdx.x * 4 + (tid >> 6);
  int nu   = *nu_ptr;
  int j = wv * 4 + g;
  const unsigned short* X = X0;
  unsigned short* Mo = M0;
  int node = 0, idx = 0;
  bool active = true;
  if (j < 2 * nu){
    int sub = (j >= nu);
    idx = j - (sub ? nu : 0);
    int row = list[idx];
    node = row + (sub ? N_CLAIM : 0);
    X = sub ? X1 : X0; Mo = sub ? M1 : M0;
  } else {
    int jj = j - 2 * nu;
    if (jj < ne){ idx = jj; node = 2 * N_CLAIM + jj; X = X2; Mo = M2; }
    else if (jj - ne < nev){ idx = jj - ne; node = 2 * N_CLAIM + N_ENTITY + idx; X = X3; Mo = M3; }
    else active = false;
  }
  int rbeg = 0, rend = 0;
  if (active){ rbeg = R[node]; rend = R[node + 1]; }
  int deg = rend - rbeg;
  float4 acc = {0.f, 0.f, 0.f, 0.f};
  for (int p = rbeg; p < rend; p += 8){
    int nb = rend - p; if (nb > 8) nb = 8;
    int cid = 0;
    if (fl < nb) cid = col[p + fl];
    #pragma unroll
    for (int k = 0; k < 8; ++k){
      int c = __shfl(cid, (g << 4) + k, 64);
      if (k < nb){
        uint2 d = *(const uint2*)(X + c * F + fl * 4);
        acc.x += __uint_as_float(d.x << 16);
        acc.y += __uint_as_float(d.x & 0xffff0000u);
        acc.z += __uint_as_float(d.y << 16);
        acc.w += __uint_as_float(d.y & 0xffff0000u);
      }
    }
  }
  if (active){
    float r = deg ? (1.0f / (float)deg) : 0.f;
    ushort4 o;
    o.x = f2b(acc.x * r); o.y = f2b(acc.y * r);
    o.z = f2b(acc.z * r); o.w = f2b(acc.w * r);
    *(ushort4*)(Mo + (long long)idx * F + fl * 4) = o;
  }
}

// ---- fused multi-source GEMM: H = act(sum_j Aj@Wj + bias) ----
typedef __bf16 bf16x8 __attribute__((ext_vector_type(8)));
typedef float  f32x4  __attribute__((ext_vector_type(4)));
#define WT_STRIDE 72

__global__ __launch_bounds__(256) void k_gemm(
    const unsigned short* __restrict__ A0, const unsigned short* __restrict__ A1,
    const unsigned short* __restrict__ A2, const unsigned short* __restrict__ A3,
    const float* __restrict__ W0, const float* __restrict__ W1,
    const float* __restrict__ W2, const float* __restrict__ W3,
    const float* __restrict__ b0, const float* __restrict__ b1,
    unsigned short* __restrict__ Hout,
    const int* __restrict__ Alist, int amask,
    const int* __restrict__ Mptr, int Mparam, int ns, int relu)
{
  int M = Mptr ? *Mptr : Mparam;
  if ((int)blockIdx.x * 64 >= M) return;
  __shared__ __align__(16) unsigned short WT[4 * 64 * WT_STRIDE];
  const float* Ws[4] = {W0, W1, W2, W3};
  const unsigned short* As[4] = {A0, A1, A2, A3};
  int tid = threadIdx.x;
  for (int j = 0; j < ns; j++){
    const float* Wj = Ws[j];
    #pragma unroll
    for (int q = 0; q < 16; q++){
      int idx = q * 256 + tid;
      int k = idx >> 6, n = idx & 63;
      WT[j * 64 * WT_STRIDE + n * WT_STRIDE + k] = f2b(Wj[idx]);
    }
  }
  __syncthreads();
  int wave = tid >> 6, lane = tid & 63;
  int quad = lane >> 4, l16 = lane & 15;
  int m0 = blockIdx.x * 64 + wave * 16;
  int arow = m0 + l16; if (arow >= M) arow = M - 1;
  int arows[4];
  #pragma unroll
  for (int j = 0; j < 4; j++)
    arows[j] = ((amask >> j) & 1) ? Alist[arow] : arow;
  f32x4 z = {0.f, 0.f, 0.f, 0.f};
  f32x4 acc[4] = {z, z, z, z};
  for (int j = 0; j < ns; j++){
    const unsigned short* Aj = As[j];
    #pragma unroll
    for (int kk = 0; kk < 64; kk += 32){
      bf16x8 af = *(const bf16x8*)(Aj + (long long)arows[j] * F + kk + quad * 8);
      #pragma unroll
      for (int c = 0; c < 4; c++){
        const unsigned short* bp = &WT[j * 64 * WT_STRIDE + (c * 16 + l16) * WT_STRIDE + kk + quad * 8];
        bf16x8 bfr = *(const bf16x8*)bp;
        acc[c] = __builtin_amdgcn_mfma_f32_16x16x32_bf16(af, bfr, acc[c], 0, 0, 0);
      }
    }
  }
  #pragma unroll
  for (int c = 0; c < 4; c++){
    int n = c * 16 + l16;
    float bv = b0[n] + (b1 ? b1[n] : 0.f);
    #pragma unroll
    for (int r = 0; r < 4; r++){
      int row = m0 + quad * 4 + r;
      if (row < M){
        float v = acc[c][r] + bv;
        if (relu) v = fmaxf(v, 0.f);
        Hout[(long long)row * F + n] = f2b(v);
      }
    }
  }
}

// ---------------- final classifier: wave per batch row; fp32 out ----------------
__global__ void k_out(const unsigned short* __restrict__ h2,
                      const int* __restrict__ cbi,
                      const int* __restrict__ rank,
                      const float* __restrict__ Wc,
                      const float* __restrict__ bcp,
                      float* __restrict__ out){
  int w = (int)(((unsigned)blockIdx.x * blockDim.x + threadIdx.x) >> 6);
  int lane = threadIdx.x & 63;
  if (w >= BATCH) return;
  int rk = rank[cbi[w]];
  float v = b2f(h2[(long long)rk * F + lane]);
  float p0 = v * Wc[lane * 2];
  float p1 = v * Wc[lane * 2 + 1];
  for (int off = 32; off; off >>= 1){
    p0 += __shfl_xor(p0, off, 64);
    p1 += __shfl_xor(p1, off, 64);
  }
  if (lane == 0){
    out[2 * w]     = p0 + bcp[0];
    out[2 * w + 1] = p1 + bcp[1];
  }
}

extern "C" void kernel_launch(void* const* d_in, const int* in_sizes, int n_in,
                              void* d_out, int out_size, void* d_ws, size_t ws_size,
                              hipStream_t stream)
{
  const float* x_c = (const float*)d_in[0];
  const float* x_e = (const float*)d_in[1];
  const float* x_v = (const float*)d_in[2];
  const int*   ei  = (const int*)d_in[3];
  const int*   cbi = (const int*)d_in[4];
  const float* Wl1 = (const float*)d_in[5];
  const float* bl1 = (const float*)d_in[6];
  const float* Wr1 = (const float*)d_in[7];
  const float* Wl2 = (const float*)d_in[8];
  const float* bl2 = (const float*)d_in[9];
  const float* Wr2 = (const float*)d_in[10];
  const float* Wc  = (const float*)d_in[11];
  const float* bc  = (const float*)d_in[12];
  float* out = (float*)d_out;

  char* ws = (char*)d_ws;
  size_t off = 0;
  auto alloc = [&](size_t bytes) -> char* {
    char* p = ws + off;
    off += (bytes + 255) & ~(size_t)255;
    return p;
  };
  int* R       = (int*)alloc((size_t)(NT + 1) * 4);
  int* cursor  = (int*)alloc((size_t)NBKT * 4);
  int* colBase = (int*)alloc((size_t)NBKT * 4);
  int* flag    = (int*)alloc((size_t)N_CLAIM * 4);
  int* rank    = (int*)alloc((size_t)N_CLAIM * 4);
  int* list    = (int*)alloc((size_t)BATCH * 4);
  int* nu      = (int*)alloc(256);
  int* col     = (int*)alloc((size_t)4 * NEDGE * 4);
  unsigned int* pairs = (unsigned int*)alloc((size_t)NBKT * CAP * 4);   // 30.9 MB, dead after k_csr
  unsigned short* xb_c  = (unsigned short*)alloc((size_t)N_CLAIM    * F * 2);  // contiguous with
  unsigned short* xb_e  = (unsigned short*)alloc((size_t)N_ENTITY   * F * 2);  // xb_e / xb_v (sizes
  unsigned short* xb_v  = (unsigned short*)alloc((size_t)N_EVIDENCE * F * 2);  // are 256B multiples)
  unsigned short* mean0 = (unsigned short*)alloc((size_t)BATCH * F * 2);
  unsigned short* mean1 = (unsigned short*)alloc((size_t)BATCH * F * 2);
  unsigned short* h1c   = (unsigned short*)alloc((size_t)BATCH * F * 2);
  unsigned short* h1e   = (unsigned short*)alloc((size_t)N_ENTITY   * F * 2);
  unsigned short* h1v   = (unsigned short*)alloc((size_t)N_EVIDENCE * F * 2);
  unsigned short* mean3 = (unsigned short*)alloc((size_t)N_EVIDENCE * F * 2);
  unsigned short* mean2 = (unsigned short*)pairs;   // 25.6 MB <= 30.9 MB, pairs dead after k_csr
  unsigned short* h2c   = mean2;                    // mean2 dead after entity GEMM

  hipMemsetAsync(flag, 0, (size_t)N_CLAIM * 4, stream);
  hipMemsetAsync(nu, 0, 4, stream);

  k_mark<<<(BATCH + 255) / 256, 256, 0, stream>>>(cbi, flag, cursor);
  k_rank<<<(N_CLAIM + 255) / 256, 256, 0, stream>>>(flag, rank, list, nu);
  {
    int n4 = (N_CLAIM + N_ENTITY + N_EVIDENCE) * F / 4;
    k_cast3<<<(n4 + 255) / 256, 256, 0, stream>>>(x_c, x_e, x_v, xb_c);
  }

  k_bscatter<<<B3_BLOCKS, 256, 0, stream>>>(ei, flag, cursor, pairs);
  k_bscan<<<1, 1024, 0, stream>>>(cursor, colBase, R);
  k_csr<<<NBKT * 4, 256, 0, stream>>>(pairs, cursor, colBase, R, col);

  // ---- layer 1 aggregation: claims + entity + evidence in one dispatch ----
  {
    int njobs = 2 * BATCH + N_ENTITY + N_EVIDENCE;
    k_agg4<<<(njobs + 15) / 16, 256, 0, stream>>>(
        xb_e, xb_v, xb_c, xb_c, R, col, mean0, mean1, mean2, mean3,
        list, nu, N_ENTITY, N_EVIDENCE);
  }

  // ---- layer 1 transforms ----
  k_gemm<<<(BATCH + 63) / 64, 256, 0, stream>>>(mean0, mean1, xb_c, xb_c,
        Wl1, Wl1 + 4096, Wr1, Wr1 + 4096, bl1, bl1 + 64, h1c,
        list, 0b1100, nu, 0, 4, 1);
  k_gemm<<<(N_ENTITY + 63) / 64, 256, 0, stream>>>(mean2, xb_e, nullptr, nullptr,
        Wl1 + 2 * 4096, Wr1 + 2 * 4096, nullptr, nullptr, bl1 + 128, nullptr, h1e,
        nullptr, 0, nullptr, N_ENTITY, 2, 1);
  k_gemm<<<(N_EVIDENCE + 63) / 64, 256, 0, stream>>>(mean3, xb_v, nullptr, nullptr,
        Wl1 + 3 * 4096, Wr1 + 3 * 4096, nullptr, nullptr, bl1 + 192, nullptr, h1v,
        nullptr, 0, nullptr, N_EVIDENCE, 2, 1);

  // ---- layer 2: claims only, compacted ----
  k_agg4<<<(2 * BATCH + 15) / 16, 256, 0, stream>>>(
      h1e, h1v, nullptr, nullptr, R, col, mean0, mean1, nullptr, nullptr,
      list, nu, 0, 0);
  k_gemm<<<(BATCH + 63) / 64, 256, 0, stream>>>(mean0, mean1, h1c, h1c,
        Wl2, Wl2 + 4096, Wr2, Wr2 + 4096, bl2, bl2 + 64, h2c,
        nullptr, 0, nu, 0, 4, 0);

  // ---- classifier ----
  k_out<<<(BATCH * 64 + 255) / 256, 256, 0, stream>>>(h2c, cbi, rank, Wc, bc, out);
}